// Round 1
// baseline (388.390 us; speedup 1.0000x reference)
//
#include <hip/hip_runtime.h>

#define EPS 1e-6f

constexpr int KNB = 32;            // K neighbors
constexpr int NFG = 4;
constexpr int NH  = 16;
constexpr int NFO = 32;
constexpr int FH  = NFG * NH;      // 64
constexpr int ACN = KNB * FH;      // 2048 ac elems per row
constexpr int ON  = NFO * NH;      // 512 output elems per row
constexpr int KN  = KNB * NH;      // 512 attn elems per row

__global__ __launch_bounds__(256, 4)
void attn_fused(const float* __restrict__ beta,
                const float* __restrict__ sa,
                const float* __restrict__ ac,
                const float* __restrict__ no,
                const float* __restrict__ gw,
                float* __restrict__ out,       // [BL, 512]
                float* __restrict__ attn_out)  // [BL, 512]
{
    const int bl   = blockIdx.x;
    const int tid  = threadIdx.x;
    const int lane = tid & 63;
    const int wv   = tid >> 6;      // wave id 0..3

    __shared__ float s_ac[ACN];        // gated ac, [k*64 + f*16 + h]
    __shared__ float s_attn[KN];       // normalized attn, [k*16 + h]
    __shared__ float s_wm[4 * NH];     // per-wave per-h max
    __shared__ float s_wd[4 * NH];     // per-wave per-h abs-sum

    const size_t blz = (size_t)bl;
    const float* acp = ac + blz * ACN;
    const float* nop = no + blz * (size_t)(KNB * ON);

    const int h  = tid & 15;
    const int k0 = tid >> 4;        // 0..15

    // ---- issue long-latency broadcast loads up front (no LDS, no barrier) ----
    // gw for exp phase: thread needs rows k0 and k0+16 only.
    const float4 gw0 = *reinterpret_cast<const float4*>(gw + blz * (KNB * NFG) + k0 * 4);
    const float4 gw1 = *reinterpret_cast<const float4*>(gw + blz * (KNB * NFG) + (k0 + 16) * 4);
    // beta gate: column (tid + j*256) & 63 == tid & 63 for all j  -> one scalar.
    const float bg = beta[blz * FH + (tid & 63)] + EPS;

    // ---- load + gate ac; h-class is constant per thread (256 % 16 == 0) ----
    float lmax = -INFINITY;
    #pragma unroll
    for (int j = 0; j < 8; ++j) {
        const int idx = tid + j * 256;
        float v = acp[idx];
        if (j == 0 && tid < FH) v += sa[blz * FH + tid];  // k==0 slot
        v *= bg;
        s_ac[idx] = v;
        lmax = fmaxf(lmax, v);
    }

    // ---- prefetch node_out k=0..7 into registers; consumed after the last
    //      barrier, so HBM latency hides under the whole softmax chain. ----
    const int p2 = tid * 2;            // output pair base, 8B aligned
    const int hp = p2 & 15;
    const float* npp = nop + p2;
    float2 v[8];
    #pragma unroll
    for (int k = 0; k < 8; ++k)
        v[k] = *reinterpret_cast<const float2*>(npp + k * ON);

    // ---- per-h max: intra-wave shuffle, one barrier cross-wave ----
    lmax = fmaxf(lmax, __shfl_xor(lmax, 16, 64));
    lmax = fmaxf(lmax, __shfl_xor(lmax, 32, 64));
    if (lane < 16) s_wm[wv * 16 + lane] = lmax;
    __syncthreads();   // also publishes s_ac
    const float m = fmaxf(fmaxf(s_wm[h], s_wm[16 + h]),
                          fmaxf(s_wm[32 + h], s_wm[48 + h]));

    // ---- exp, gw-weight, sum over f: 2 (k,h) pairs per thread ----
    const float* r0 = s_ac + k0 * 64 + h;
    float a0 = __expf(r0[ 0] - m) * gw0.x
             + __expf(r0[16] - m) * gw0.y
             + __expf(r0[32] - m) * gw0.z
             + __expf(r0[48] - m) * gw0.w;
    const float* r1 = s_ac + (k0 + 16) * 64 + h;
    float a1 = __expf(r1[ 0] - m) * gw1.x
             + __expf(r1[16] - m) * gw1.y
             + __expf(r1[32] - m) * gw1.z
             + __expf(r1[48] - m) * gw1.w;

    // ---- per-h abs-sum over k: same shuffle pattern ----
    float ls = fabsf(a0) + fabsf(a1);
    ls += __shfl_xor(ls, 16, 64);
    ls += __shfl_xor(ls, 32, 64);
    if (lane < 16) s_wd[wv * 16 + lane] = ls;
    __syncthreads();
    const float den = s_wd[h] + s_wd[16 + h] + s_wd[32 + h] + s_wd[48 + h] + EPS;

    const float n0 = a0 / den;
    const float n1 = a1 / den;
    s_attn[tid]       = n0;          // k0*16+h == tid
    s_attn[tid + 256] = n1;          // (k0+16)*16+h == tid+256
    attn_out[blz * KN + tid]       = n0;
    attn_out[blz * KN + tid + 256] = n1;
    __syncthreads();

    // ---- einsum over all 32 k, float2 per thread, rolling 8-deep prefetch.
    //      out[p] = sum_k no[k*512+p] * attn[k*16+(p&15)]
    //      No even/odd split: no combine barrier, no s_part, no idle tail. ----
    float2 acc = make_float2(0.f, 0.f);
    #pragma unroll
    for (int k = 0; k < KNB; ++k) {
        const float2 w = *reinterpret_cast<const float2*>(&s_attn[k * 16 + hp]);
        const float2 x = v[k & 7];
        if (k < KNB - 8)
            v[k & 7] = *reinterpret_cast<const float2*>(npp + (k + 8) * ON);
        acc.x += x.x * w.x;
        acc.y += x.y * w.y;
    }
    *reinterpret_cast<float2*>(out + blz * ON + p2) = acc;
}

extern "C" void kernel_launch(void* const* d_in, const int* in_sizes, int n_in,
                              void* d_out, int out_size, void* d_ws, size_t ws_size,
                              hipStream_t stream) {
    const float* beta = (const float*)d_in[0];
    const float* sa   = (const float*)d_in[1];
    const float* ac   = (const float*)d_in[2];
    const float* no   = (const float*)d_in[3];
    const float* gw   = (const float*)d_in[4];

    const int BL = in_sizes[0] / FH;   // B*L = 4096
    float* out      = (float*)d_out;
    float* attn_out = out + (size_t)BL * ON;

    attn_fused<<<BL, 256, 0, stream>>>(beta, sa, ac, no, gw, out, attn_out);
}